// Round 4
// baseline (221.268 us; speedup 1.0000x reference)
//
#include <hip/hip_runtime.h>

// MoEAttentionBlock r4: grid-occupancy fix — BM=64 QKV / BM=32 dense grouped GEMM
// (templated), mask application moved to coalesced softmax pass.
// B=4 N=512 H=1024 NH=16 E=8 DH=64, T=2048 tokens.

typedef short short8 __attribute__((ext_vector_type(8)));
typedef float f32x4 __attribute__((ext_vector_type(4)));

constexpr int Bsz  = 4;
constexpr int Nseq = 512;
constexpr int Hdim = 1024;
constexpr int NHd  = 16;
constexpr int Ex   = 8;
constexpr int DHd  = 64;
constexpr int T    = Bsz * Nseq;   // 2048
constexpr int H3   = 3 * Hdim;     // 3072
constexpr int MAXT64 = 40;         // sum ceil(c_e/64)  <= 32+8
constexpr int MAXT32 = 72;         // sum ceil(c_e/32)  <= 64+8

__device__ inline unsigned short f2bf(float f) {
  union { float f; unsigned u; } v{f};
  unsigned r = v.u + 0x7fffu + ((v.u >> 16) & 1u);   // RNE
  return (unsigned short)(r >> 16);
}
__device__ inline float bf2f(unsigned short s) {
  union { unsigned u; float f; } v{(unsigned)s << 16};
  return v.f;
}
__device__ inline unsigned packbf(float lo, float hi) {
  return (unsigned)f2bf(lo) | ((unsigned)f2bf(hi) << 16);
}

// ---------------- init ------------------------------------------------------------
__global__ void init_kernel(int* counts) {
  if (threadIdx.x < Ex) counts[threadIdx.x] = 0;
}

// ---------------- gating ----------------------------------------------------------
__global__ __launch_bounds__(64) void gate_kernel(
    const float* __restrict__ x, const float* __restrict__ wg,
    float* __restrict__ prob, int* __restrict__ expert, int* __restrict__ counts) {
  int t = blockIdx.x;
  int l = threadIdx.x;
  const float* xr = x + (size_t)t * Hdim;
  float acc[Ex] = {0, 0, 0, 0, 0, 0, 0, 0};
  for (int h = l; h < Hdim; h += 64) {
    float xv = xr[h];
    const float4* wr = (const float4*)(wg + (size_t)h * Ex);
    float4 w0 = wr[0], w1 = wr[1];
    acc[0] += xv * w0.x; acc[1] += xv * w0.y; acc[2] += xv * w0.z; acc[3] += xv * w0.w;
    acc[4] += xv * w1.x; acc[5] += xv * w1.y; acc[6] += xv * w1.z; acc[7] += xv * w1.w;
  }
#pragma unroll
  for (int e = 0; e < Ex; e++) {
#pragma unroll
    for (int off = 32; off > 0; off >>= 1) acc[e] += __shfl_down(acc[e], off);
  }
  if (l == 0) {
    float m = acc[0]; int mi = 0;
#pragma unroll
    for (int e = 1; e < Ex; e++) if (acc[e] > m) { m = acc[e]; mi = e; }  // first-max == jnp.argmax
    float s = 0.f;
#pragma unroll
    for (int e = 0; e < Ex; e++) s += expf(acc[e] - m);
    prob[t]   = 1.0f / s;
    expert[t] = mi;
    atomicAdd(&counts[mi], 1);
  }
}

// ---------------- offsets + two tile maps (BM=64 and BM=32) -----------------------
__global__ void offsets_kernel(const int* __restrict__ counts, int* offs, int* cursor,
                               int* meta, int* te64, int* tr64, int* te32, int* tr32) {
  int o = 0, n64 = 0, n32 = 0;
  for (int e = 0; e < Ex; e++) {
    offs[e] = o; cursor[e] = o;
    int c = counts[e];
    for (int r = 0; r < c; r += 64) { te64[n64] = e; tr64[n64] = o + r; n64++; }
    for (int r = 0; r < c; r += 32) { te32[n32] = e; tr32[n32] = o + r; n32++; }
    o += c;
  }
  offs[Ex] = o;
  meta[0] = n64;
  meta[1] = n32;
}

// ---------------- scatter ---------------------------------------------------------
__global__ __launch_bounds__(256) void scatter_kernel(
    const int* __restrict__ expert, int* cursor, int* __restrict__ perm) {
  int t = blockIdx.x * 256 + threadIdx.x;
  if (t < T) {
    int slot = atomicAdd(&cursor[expert[t]], 1);
    perm[slot] = t;
  }
}

// ---------------- fp32 -> bf16 bulk convert ---------------------------------------
__global__ __launch_bounds__(256) void cvt_kernel(const float* __restrict__ x,
                                                  unsigned short* __restrict__ y, int n8) {
  int i = blockIdx.x * 256 + threadIdx.x;
  if (i < n8) {
    const float4* s = (const float4*)(x + (size_t)i * 8);
    float4 a = s[0], b = s[1];
    ushort4 lo = {f2bf(a.x), f2bf(a.y), f2bf(a.z), f2bf(a.w)};
    ushort4 hi = {f2bf(b.x), f2bf(b.y), f2bf(b.z), f2bf(b.w)};
    ushort4* d = (ushort4*)(y + (size_t)i * 8);
    d[0] = lo; d[1] = hi;
  }
}

// ---------------- grouped GEMM via MFMA, templated on row-tile --------------------
// BM_ in {64,32}. 4 waves in (4/WC)x(WC) grid. BN=128, BK=32.
// A: bf16 [BM_][40]. B: W fp32 -> Bt[col][40] transposed k-pair packed writes;
// B-frag = single ds_read_b128.
template <int BM_, int WC>
__global__ __launch_bounds__(256) void moe_gemm_mfma(
    const unsigned short* __restrict__ Xb, const float* __restrict__ W,
    const float* __restrict__ bias, const float* __restrict__ prob,
    const int* __restrict__ perm, const int* __restrict__ offs,
    const int* __restrict__ metap, const int* __restrict__ tile_e,
    const int* __restrict__ tile_r,
    unsigned short* __restrict__ Ybf, float* __restrict__ Yf, int Ncols) {
  constexpr int WR = 4 / WC;            // wave rows
  constexpr int MF = BM_ / WR / 16;     // m-frags per wave
  constexpr int NF = 128 / WC / 16;     // n-frags per wave
  int tIdx = blockIdx.y;
  if (tIdx >= metap[0]) return;
  int e = tile_e[tIdx], row0 = tile_r[tIdx];
  int rows = offs[e + 1] - row0; if (rows > BM_) rows = BM_;
  int col0 = blockIdx.x * 128;

  __shared__ unsigned short As[BM_ * 40];
  __shared__ unsigned short Bt[128 * 40];
  __shared__ int   tok_s[BM_];
  __shared__ float p_s[BM_];

  int tid = threadIdx.x;
  if (tid < BM_) {
    int rr = tid < rows ? tid : rows - 1;
    int tok = perm[row0 + rr];
    tok_s[tid] = tok; p_s[tid] = prob[tok];
  }
  __syncthreads();

  // A staging: chunk tid covers row tid>>2, 8 bf16 at (tid&3)*8. BM_*4 chunks.
  const unsigned short* asrc = nullptr;
  int ar = tid >> 2, aq = tid & 3;
  if (tid < BM_ * 4) asrc = Xb + (size_t)tok_s[ar] * Hdim + aq * 8;
  // B staging: thread owns k-pair kp, 8 cols at bc8.
  int kp = tid & 15, bc8 = (tid >> 4) * 8;
  const float* wb = W + (size_t)e * Hdim * Ncols + col0 + bc8;

  int lane = tid & 63, wave = tid >> 6;
  int wr = wave / WC, wc = wave % WC;
  int l15 = lane & 15, l4 = lane >> 4;

  f32x4 acc[MF][NF] = {};

  for (int k0 = 0; k0 < Hdim; k0 += 32) {
    uint4 av;
    if (asrc) av = *(const uint4*)(asrc + k0);
    const float* r0 = wb + (size_t)(k0 + 2 * kp) * Ncols;
    float4 wa0 = *(const float4*)(r0);
    float4 wa1 = *(const float4*)(r0 + 4);
    float4 wb0 = *(const float4*)(r0 + Ncols);
    float4 wb1 = *(const float4*)(r0 + Ncols + 4);
    __syncthreads();   // previous tile's frag reads complete
    if (asrc) *(uint4*)&As[ar * 40 + aq * 8] = av;
    *(unsigned*)&Bt[(bc8 + 0) * 40 + 2 * kp] = packbf(wa0.x, wb0.x);
    *(unsigned*)&Bt[(bc8 + 1) * 40 + 2 * kp] = packbf(wa0.y, wb0.y);
    *(unsigned*)&Bt[(bc8 + 2) * 40 + 2 * kp] = packbf(wa0.z, wb0.z);
    *(unsigned*)&Bt[(bc8 + 3) * 40 + 2 * kp] = packbf(wa0.w, wb0.w);
    *(unsigned*)&Bt[(bc8 + 4) * 40 + 2 * kp] = packbf(wa1.x, wb1.x);
    *(unsigned*)&Bt[(bc8 + 5) * 40 + 2 * kp] = packbf(wa1.y, wb1.y);
    *(unsigned*)&Bt[(bc8 + 6) * 40 + 2 * kp] = packbf(wa1.z, wb1.z);
    *(unsigned*)&Bt[(bc8 + 7) * 40 + 2 * kp] = packbf(wa1.w, wb1.w);
    __syncthreads();

    short8 a[MF];
#pragma unroll
    for (int m = 0; m < MF; m++)
      a[m] = *(const short8*)&As[(wr * (BM_ / WR) + m * 16 + l15) * 40 + l4 * 8];
#pragma unroll
    for (int n = 0; n < NF; n++) {
      short8 bfr = *(const short8*)&Bt[(wc * (128 / WC) + n * 16 + l15) * 40 + l4 * 8];
#pragma unroll
      for (int m = 0; m < MF; m++)
        acc[m][n] = __builtin_amdgcn_mfma_f32_16x16x32_bf16(a[m], bfr, acc[m][n], 0, 0, 0);
    }
  }

  // epilogue: C/D layout col=lane&15, row=(lane>>4)*4+reg  [m89]
#pragma unroll
  for (int n = 0; n < NF; n++) {
    int colg = col0 + wc * (128 / WC) + n * 16 + l15;
    float bv = bias[(size_t)e * Ncols + colg];
#pragma unroll
    for (int m = 0; m < MF; m++) {
#pragma unroll
      for (int r = 0; r < 4; r++) {
        int row = wr * (BM_ / WR) + m * 16 + l4 * 4 + r;
        if (row < rows) {
          int tok = tok_s[row];
          float o = (acc[m][n][r] + bv) * p_s[row];
          if (Ybf) Ybf[(size_t)tok * Ncols + colg] = f2bf(o);
          else     Yf [(size_t)tok * Ncols + colg] = o;
        }
      }
    }
  }
}

// ---------------- MFMA attention --------------------------------------------------
// block = (qt, h, b), 256 thr = 4 waves. 32 q-rows, 512 keys, DH=64.
// QK: wave w -> keys w*16..+15 per 64-key tile (raw scores); mask applied in
// softmax pass with coalesced int4 mask loads. PV: wave w -> d-cols w*16..+15.
__global__ __launch_bounds__(256) void attn_kernel(
    const unsigned short* __restrict__ qkvb, const int* __restrict__ attn_mask,
    const int* __restrict__ kp_mask, float* __restrict__ probs_out,
    unsigned short* __restrict__ ctxb) {
  int qt = blockIdx.x, h = blockIdx.y, b = blockIdx.z;
  int tid = threadIdx.x;

  __shared__ unsigned short Qs[32 * 72];
  __shared__ unsigned short KV[64 * 72];
  __shared__ unsigned short S[32 * 520];
  __shared__ float invs[32];

  int lane = tid & 63, wave = tid >> 6;
  int l15 = lane & 15, l4 = lane >> 4;

  // ---- Q stage, pre-scaled by 1/8 (exact pow2) ----
  {
    int r = tid >> 3, c = (tid & 7) * 8;
    int t = b * Nseq + qt * 32 + r;
    uint4 v = *(const uint4*)(qkvb + (size_t)t * H3 + h * DHd + c);
    unsigned short* u = (unsigned short*)&v;
    unsigned short tmp[8];
#pragma unroll
    for (int j = 0; j < 8; j++) tmp[j] = f2bf(bf2f(u[j]) * 0.125f);
    *(uint4*)&Qs[r * 72 + c] = *(uint4*)tmp;
  }

  // ---- QK^T (raw scores) ----
  int kr0 = tid >> 3, kc0 = (tid & 7) * 8;
  int kr1 = kr0 + 32;
  for (int kt = 0; kt < 8; kt++) {
    uint4 kv0 = *(const uint4*)(qkvb + (size_t)(b * Nseq + kt * 64 + kr0) * H3 + Hdim + h * DHd + kc0);
    uint4 kv1 = *(const uint4*)(qkvb + (size_t)(b * Nseq + kt * 64 + kr1) * H3 + Hdim + h * DHd + kc0);
    __syncthreads();   // prior tile's frag reads done (kt=0: orders Q write too)
    *(uint4*)&KV[kr0 * 72 + kc0] = kv0;
    *(uint4*)&KV[kr1 * 72 + kc0] = kv1;
    __syncthreads();

    f32x4 acc[2] = {};
#pragma unroll
    for (int kk = 0; kk < 2; kk++) {
      short8 bfr = *(const short8*)&KV[(wave * 16 + l15) * 72 + kk * 32 + l4 * 8];
#pragma unroll
      for (int m = 0; m < 2; m++) {
        short8 afr = *(const short8*)&Qs[(m * 16 + l15) * 72 + kk * 32 + l4 * 8];
        acc[m] = __builtin_amdgcn_mfma_f32_16x16x32_bf16(afr, bfr, acc[m], 0, 0, 0);
      }
    }
    int key = kt * 64 + wave * 16 + l15;
#pragma unroll
    for (int m = 0; m < 2; m++) {
#pragma unroll
      for (int r = 0; r < 4; r++) {
        int row = m * 16 + l4 * 4 + r;
        S[row * 520 + key] = f2bf(acc[m][r]);
      }
    }
  }
  __syncthreads();

  // ---- mask + softmax: 8 lanes/row; S <- exp(masked - m) unnormalized ----
  float inv;
  int sr = tid >> 3, sg = tid & 7;
  {
    unsigned short* Srow = &S[sr * 520];
    const int* amrow = attn_mask + (qt * 32 + sr) * Nseq;
    const int* kprow = kp_mask + b * Nseq;
    float m = -3.0e38f;
#pragma unroll
    for (int i = 0; i < 8; i++) {
      int cb = (sg + 8 * i) * 8;
      uint4 v = *(const uint4*)&Srow[cb];
      unsigned short* u = (unsigned short*)&v;
      int4 a0 = *(const int4*)(amrow + cb);
      int4 a1 = *(const int4*)(amrow + cb + 4);
      int4 k0 = *(const int4*)(kprow + cb);
      int4 k1 = *(const int4*)(kprow + cb + 4);
      float s[8];
      s[0] = bf2f(u[0]) + ((a0.x | k0.x) ? -10000.0f : 0.0f);
      s[1] = bf2f(u[1]) + ((a0.y | k0.y) ? -10000.0f : 0.0f);
      s[2] = bf2f(u[2]) + ((a0.z | k0.z) ? -10000.0f : 0.0f);
      s[3] = bf2f(u[3]) + ((a0.w | k0.w) ? -10000.0f : 0.0f);
      s[4] = bf2f(u[4]) + ((a1.x | k1.x) ? -10000.0f : 0.0f);
      s[5] = bf2f(u[5]) + ((a1.y | k1.y) ? -10000.0f : 0.0f);
      s[6] = bf2f(u[6]) + ((a1.z | k1.z) ? -10000.0f : 0.0f);
      s[7] = bf2f(u[7]) + ((a1.w | k1.w) ? -10000.0f : 0.0f);
      unsigned short t2[8];
#pragma unroll
      for (int j = 0; j < 8; j++) { t2[j] = f2bf(s[j]); m = fmaxf(m, s[j]); }
      *(uint4*)&Srow[cb] = *(uint4*)t2;
    }
#pragma unroll
    for (int off = 1; off < 8; off <<= 1) m = fmaxf(m, __shfl_xor(m, off));
    float sum = 0.f;
#pragma unroll
    for (int i = 0; i < 8; i++) {
      int cb = (sg + 8 * i) * 8;
      uint4 v = *(const uint4*)&Srow[cb];
      unsigned short* u = (unsigned short*)&v;
      unsigned short t2[8];
#pragma unroll
      for (int j = 0; j < 8; j++) {
        float p = expf(bf2f(u[j]) - m);
        t2[j] = f2bf(p);
        sum += p;
      }
      *(uint4*)&Srow[cb] = *(uint4*)t2;
    }
#pragma unroll
    for (int off = 1; off < 8; off <<= 1) sum += __shfl_xor(sum, off);
    inv = 1.0f / sum;
    if (sg == 0) invs[sr] = inv;
  }
  __syncthreads();

  // ---- probs out: fp32, normalized on the fly ----
  {
    float* dst = probs_out + (((size_t)(b * NHd + h) * Nseq + qt * 32 + sr) * Nseq);
    const unsigned short* Srow = &S[sr * 520];
#pragma unroll
    for (int i = 0; i < 8; i++) {
      int cb = (sg + 8 * i) * 8;
      uint4 v = *(const uint4*)&Srow[cb];
      unsigned short* u = (unsigned short*)&v;
      float4 o0 = {bf2f(u[0]) * inv, bf2f(u[1]) * inv, bf2f(u[2]) * inv, bf2f(u[3]) * inv};
      float4 o1 = {bf2f(u[4]) * inv, bf2f(u[5]) * inv, bf2f(u[6]) * inv, bf2f(u[7]) * inv};
      *(float4*)(dst + cb)     = o0;
      *(float4*)(dst + cb + 4) = o1;
    }
  }

  // ---- PV: ctx = (S @ V) * inv ----
  f32x4 acc2[2] = {};
  int kpair = tid & 31, vc = (tid >> 5) * 8;
  for (int kt = 0; kt < 8; kt++) {
    const unsigned short* vsrc =
        qkvb + (size_t)(b * Nseq + kt * 64 + kpair * 2) * H3 + 2 * Hdim + h * DHd + vc;
    uint4 v0 = *(const uint4*)vsrc;
    uint4 v1 = *(const uint4*)(vsrc + H3);
    __syncthreads();   // prior tile's frag reads done (kt=0: probs reads done)
    unsigned* a0 = (unsigned*)&v0;
    unsigned* a1 = (unsigned*)&v1;
#pragma unroll
    for (int i = 0; i < 4; i++) {
      unsigned lo = (a0[i] & 0xffffu) | (a1[i] << 16);
      unsigned hi = (a0[i] >> 16) | (a1[i] & 0xffff0000u);
      *(unsigned*)&KV[(vc + 2 * i    ) * 72 + 2 * kpair] = lo;   // Vt[d][keypair]
      *(unsigned*)&KV[(vc + 2 * i + 1) * 72 + 2 * kpair] = hi;
    }
    __syncthreads();
#pragma unroll
    for (int kk = 0; kk < 2; kk++) {
      short8 bfr = *(const short8*)&KV[(wave * 16 + l15) * 72 + kk * 32 + l4 * 8];
#pragma unroll
      for (int m = 0; m < 2; m++) {
        short8 pfr = *(const short8*)&S[(m * 16 + l15) * 520 + kt * 64 + kk * 32 + l4 * 8];
        acc2[m] = __builtin_amdgcn_mfma_f32_16x16x32_bf16(pfr, bfr, acc2[m], 0, 0, 0);
      }
    }
  }
#pragma unroll
  for (int m = 0; m < 2; m++) {
#pragma unroll
    for (int r = 0; r < 4; r++) {
      int row = m * 16 + l4 * 4 + r;
      int tq = b * Nseq + qt * 32 + row;
      ctxb[(size_t)tq * Hdim + h * DHd + wave * 16 + l15] = f2bf(acc2[m][r] * invs[row]);
    }
  }
}

// ---------------- host ------------------------------------------------------------
extern "C" void kernel_launch(void* const* d_in, const int* in_sizes, int n_in,
                              void* d_out, int out_size, void* d_ws, size_t ws_size,
                              hipStream_t stream) {
  const float* hidden   = (const float*)d_in[0];
  const int*   attn_m   = (const int*)d_in[1];
  const int*   kp_m     = (const int*)d_in[2];
  const float* w_gate   = (const float*)d_in[3];
  const float* w_qkv    = (const float*)d_in[4];
  const float* b_qkv    = (const float*)d_in[5];
  const float* w_dense  = (const float*)d_in[6];
  const float* b_dense  = (const float*)d_in[7];

  float* out       = (float*)d_out;                 // [T,H] fp32
  float* probs_out = out + (size_t)T * Hdim;        // [B,NH,N,N] fp32

  float*          prob = (float*)d_ws;
  unsigned short* Xb   = (unsigned short*)(prob + 2048);
  unsigned short* qkvb = Xb + (size_t)T * Hdim;
  unsigned short* ctxb = qkvb + (size_t)T * H3;
  int*   ip     = (int*)(ctxb + (size_t)T * Hdim);
  int*   expert = ip;
  int*   perm   = ip + T;
  int*   counts = ip + 2 * T;
  int*   offs   = counts + 8;
  int*   cursor = offs + 12;
  int*   meta   = cursor + 8;
  int*   te64   = meta + 4;
  int*   tr64   = te64 + MAXT64;
  int*   te32   = tr64 + MAXT64;
  int*   tr32   = te32 + MAXT32;

  init_kernel<<<1, 64, 0, stream>>>(counts);
  gate_kernel<<<T, 64, 0, stream>>>(hidden, w_gate, prob, expert, counts);
  offsets_kernel<<<1, 1, 0, stream>>>(counts, offs, cursor, meta, te64, tr64, te32, tr32);
  scatter_kernel<<<T / 256, 256, 0, stream>>>(expert, cursor, perm);
  cvt_kernel<<<(T * Hdim / 8) / 256, 256, 0, stream>>>(hidden, Xb, T * Hdim / 8);
  moe_gemm_mfma<64, 2><<<dim3(H3 / 128, MAXT64), 256, 0, stream>>>(
      Xb, w_qkv, b_qkv, prob, perm, offs, meta, te64, tr64, qkvb, nullptr, H3);
  attn_kernel<<<dim3(16, NHd, Bsz), 256, 0, stream>>>(qkvb, attn_m, kp_m, probs_out, ctxb);
  moe_gemm_mfma<32, 4><<<dim3(Hdim / 128, MAXT32), 256, 0, stream>>>(
      ctxb, w_dense, b_dense, prob, perm, offs, meta + 1, te32, tr32, nullptr, out, Hdim);
}

// Round 5
// 177.354 us; speedup vs baseline: 1.2476x; 1.2476x over previous
//
#include <hip/hip_runtime.h>

// MoEAttentionBlock r5: software-pipelined grouped GEMM (dbuf LDS, raw s_barrier,
// loads in flight across barrier), BM=128/64 BN=64. Attention = r4 (mask in softmax).
// B=4 N=512 H=1024 NH=16 E=8 DH=64, T=2048 tokens.

typedef short short8 __attribute__((ext_vector_type(8)));
typedef float f32x4 __attribute__((ext_vector_type(4)));

constexpr int Bsz  = 4;
constexpr int Nseq = 512;
constexpr int Hdim = 1024;
constexpr int NHd  = 16;
constexpr int Ex   = 8;
constexpr int DHd  = 64;
constexpr int T    = Bsz * Nseq;   // 2048
constexpr int H3   = 3 * Hdim;     // 3072
constexpr int MAXT128 = 24;        // sum ceil(c_e/128) <= 16+8
constexpr int MAXT64  = 40;        // sum ceil(c_e/64)  <= 32+8

__device__ inline unsigned short f2bf(float f) {
  union { float f; unsigned u; } v{f};
  unsigned r = v.u + 0x7fffu + ((v.u >> 16) & 1u);   // RNE
  return (unsigned short)(r >> 16);
}
__device__ inline float bf2f(unsigned short s) {
  union { unsigned u; float f; } v{(unsigned)s << 16};
  return v.f;
}
__device__ inline unsigned packbf(float lo, float hi) {
  return (unsigned)f2bf(lo) | ((unsigned)f2bf(hi) << 16);
}

// ---------------- init ------------------------------------------------------------
__global__ void init_kernel(int* counts) {
  if (threadIdx.x < Ex) counts[threadIdx.x] = 0;
}

// ---------------- gating ----------------------------------------------------------
__global__ __launch_bounds__(64) void gate_kernel(
    const float* __restrict__ x, const float* __restrict__ wg,
    float* __restrict__ prob, int* __restrict__ expert, int* __restrict__ counts) {
  int t = blockIdx.x;
  int l = threadIdx.x;
  const float* xr = x + (size_t)t * Hdim;
  float acc[Ex] = {0, 0, 0, 0, 0, 0, 0, 0};
  for (int h = l; h < Hdim; h += 64) {
    float xv = xr[h];
    const float4* wr = (const float4*)(wg + (size_t)h * Ex);
    float4 w0 = wr[0], w1 = wr[1];
    acc[0] += xv * w0.x; acc[1] += xv * w0.y; acc[2] += xv * w0.z; acc[3] += xv * w0.w;
    acc[4] += xv * w1.x; acc[5] += xv * w1.y; acc[6] += xv * w1.z; acc[7] += xv * w1.w;
  }
#pragma unroll
  for (int e = 0; e < Ex; e++) {
#pragma unroll
    for (int off = 32; off > 0; off >>= 1) acc[e] += __shfl_down(acc[e], off);
  }
  if (l == 0) {
    float m = acc[0]; int mi = 0;
#pragma unroll
    for (int e = 1; e < Ex; e++) if (acc[e] > m) { m = acc[e]; mi = e; }  // first-max == jnp.argmax
    float s = 0.f;
#pragma unroll
    for (int e = 0; e < Ex; e++) s += expf(acc[e] - m);
    prob[t]   = 1.0f / s;
    expert[t] = mi;
    atomicAdd(&counts[mi], 1);
  }
}

// ---------------- offsets + tile maps (BM=128 and BM=64) --------------------------
__global__ void offsets_kernel(const int* __restrict__ counts, int* offs, int* cursor,
                               int* meta, int* te128, int* tr128, int* te64, int* tr64) {
  int o = 0, n128 = 0, n64 = 0;
  for (int e = 0; e < Ex; e++) {
    offs[e] = o; cursor[e] = o;
    int c = counts[e];
    for (int r = 0; r < c; r += 128) { te128[n128] = e; tr128[n128] = o + r; n128++; }
    for (int r = 0; r < c; r += 64)  { te64[n64] = e;  tr64[n64] = o + r;  n64++; }
    o += c;
  }
  offs[Ex] = o;
  meta[0] = n128;
  meta[1] = n64;
}

// ---------------- scatter ---------------------------------------------------------
__global__ __launch_bounds__(256) void scatter_kernel(
    const int* __restrict__ expert, int* cursor, int* __restrict__ perm) {
  int t = blockIdx.x * 256 + threadIdx.x;
  if (t < T) {
    int slot = atomicAdd(&cursor[expert[t]], 1);
    perm[slot] = t;
  }
}

// ---------------- fp32 -> bf16 bulk convert ---------------------------------------
__global__ __launch_bounds__(256) void cvt_kernel(const float* __restrict__ x,
                                                  unsigned short* __restrict__ y, int n8) {
  int i = blockIdx.x * 256 + threadIdx.x;
  if (i < n8) {
    const float4* s = (const float4*)(x + (size_t)i * 8);
    float4 a = s[0], b = s[1];
    ushort4 lo = {f2bf(a.x), f2bf(a.y), f2bf(a.z), f2bf(a.w)};
    ushort4 hi = {f2bf(b.x), f2bf(b.y), f2bf(b.z), f2bf(b.w)};
    ushort4* d = (ushort4*)(y + (size_t)i * 8);
    d[0] = lo; d[1] = hi;
  }
}

// ---------------- pipelined grouped GEMM ------------------------------------------
// BM_ in {128,64}, BN=64, BK=32. 4 waves 2x2. Double-buffered LDS, one raw
// s_barrier per K-step; next tile's global loads stay in flight across it
// (manual lgkmcnt(0) only — no vmcnt drain at the barrier).
template <int BM_>
__global__ __launch_bounds__(256) void moe_gemm_pipe(
    const unsigned short* __restrict__ Xb, const float* __restrict__ W,
    const float* __restrict__ bias, const float* __restrict__ prob,
    const int* __restrict__ perm, const int* __restrict__ offs,
    const int* __restrict__ metap, const int* __restrict__ tile_e,
    const int* __restrict__ tile_r,
    unsigned short* __restrict__ Ybf, float* __restrict__ Yf, int Ncols) {
  constexpr int NA  = BM_ / 64;        // A uint4 chunks per thread (2 or 1)
  constexpr int MF  = BM_ / 2 / 16;    // m-frags per wave (wave grid 2x2)
  constexpr int NF  = 2;               // 64/2/16
  constexpr int ASZ = BM_ * 40;
  constexpr int BSZ = 64 * 40;

  int tIdx = blockIdx.y;
  if (tIdx >= metap[0]) return;
  int e = tile_e[tIdx], row0 = tile_r[tIdx];
  int rows = offs[e + 1] - row0; if (rows > BM_) rows = BM_;
  int col0 = blockIdx.x * 64;

  __shared__ unsigned short As[2 * ASZ];
  __shared__ unsigned short Bt[2 * BSZ];
  __shared__ int   tok_s[BM_];
  __shared__ float p_s[BM_];

  int tid = threadIdx.x;
  if (tid < BM_) {
    int rr = tid < rows ? tid : rows - 1;
    int tok = perm[row0 + rr];
    tok_s[tid] = tok; p_s[tid] = prob[tok];
  }
  __syncthreads();

  // A staging: thread covers row ar (and ar+64 if BM=128), 8 bf16 at aq*8.
  int ar = tid >> 2, aq = tid & 3;
  const unsigned short* asrc0 = Xb + (size_t)tok_s[ar] * Hdim + aq * 8;
  const unsigned short* asrc1 = asrc0;
  if constexpr (NA == 2) asrc1 = Xb + (size_t)tok_s[ar + 64] * Hdim + aq * 8;
  // B staging: thread owns k-pair kp, 4 cols at c4.
  int kp = tid & 15, c4 = (tid >> 4) * 4;
  const float* wb = W + (size_t)e * Hdim * Ncols + col0 + c4;

  int lane = tid & 63, wave = tid >> 6;
  int wr = wave >> 1, wc = wave & 1;
  int l15 = lane & 15, l4 = lane >> 4;

  f32x4 acc[MF][NF] = {};

  // prologue: load tile k0=0 into regs
  uint4 aC0 = *(const uint4*)(asrc0);
  uint4 aC1 = {};
  if constexpr (NA == 2) aC1 = *(const uint4*)(asrc1);
  const float* rp = wb;
  float4 bC0 = *(const float4*)(rp + (size_t)(2 * kp) * Ncols);
  float4 bC1 = *(const float4*)(rp + (size_t)(2 * kp + 1) * Ncols);

  int cur = 0;
  for (int k0 = 0; k0 < Hdim; k0 += 32) {
    // issue next tile's loads (stay in flight across the barrier)
    int k1 = (k0 + 32 < Hdim) ? k0 + 32 : 0;   // last iter: harmless dummy reload
    uint4 aN0 = *(const uint4*)(asrc0 + k1);
    uint4 aN1 = {};
    if constexpr (NA == 2) aN1 = *(const uint4*)(asrc1 + k1);
    float4 bN0 = *(const float4*)(wb + (size_t)(k1 + 2 * kp) * Ncols);
    float4 bN1 = *(const float4*)(wb + (size_t)(k1 + 2 * kp + 1) * Ncols);

    // write current tile (compiler inserts counted vmcnt for the reg deps)
    unsigned short* As_ = As + cur * ASZ;
    unsigned short* Bt_ = Bt + cur * BSZ;
    *(uint4*)&As_[ar * 40 + aq * 8] = aC0;
    if constexpr (NA == 2) *(uint4*)&As_[(ar + 64) * 40 + aq * 8] = aC1;
    *(unsigned*)&Bt_[(c4 + 0) * 40 + 2 * kp] = packbf(bC0.x, bC1.x);
    *(unsigned*)&Bt_[(c4 + 1) * 40 + 2 * kp] = packbf(bC0.y, bC1.y);
    *(unsigned*)&Bt_[(c4 + 2) * 40 + 2 * kp] = packbf(bC0.z, bC1.z);
    *(unsigned*)&Bt_[(c4 + 3) * 40 + 2 * kp] = packbf(bC0.w, bC1.w);
    asm volatile("s_waitcnt lgkmcnt(0)" ::: "memory");   // own LDS writes done
    __builtin_amdgcn_s_barrier();                        // no vmcnt drain here
    asm volatile("" ::: "memory");

    short8 a[MF];
#pragma unroll
    for (int m = 0; m < MF; m++)
      a[m] = *(const short8*)&As_[(wr * (BM_ / 2) + m * 16 + l15) * 40 + l4 * 8];
#pragma unroll
    for (int n = 0; n < NF; n++) {
      short8 bfr = *(const short8*)&Bt_[(wc * 32 + n * 16 + l15) * 40 + l4 * 8];
#pragma unroll
      for (int m = 0; m < MF; m++)
        acc[m][n] = __builtin_amdgcn_mfma_f32_16x16x32_bf16(a[m], bfr, acc[m][n], 0, 0, 0);
    }
    aC0 = aN0; aC1 = aN1; bC0 = bN0; bC1 = bN1;
    cur ^= 1;
  }

  // epilogue: C/D layout col=lane&15, row=(lane>>4)*4+reg  [m89]
#pragma unroll
  for (int n = 0; n < NF; n++) {
    int colg = col0 + wc * 32 + n * 16 + l15;
    float bv = bias[(size_t)e * Ncols + colg];
#pragma unroll
    for (int m = 0; m < MF; m++) {
#pragma unroll
      for (int r = 0; r < 4; r++) {
        int row = wr * (BM_ / 2) + m * 16 + l4 * 4 + r;
        if (row < rows) {
          int tok = tok_s[row];
          float o = (acc[m][n][r] + bv) * p_s[row];
          if (Ybf) Ybf[(size_t)tok * Ncols + colg] = f2bf(o);
          else     Yf [(size_t)tok * Ncols + colg] = o;
        }
      }
    }
  }
}

// ---------------- MFMA attention (r4: mask applied in softmax pass) ---------------
__global__ __launch_bounds__(256) void attn_kernel(
    const unsigned short* __restrict__ qkvb, const int* __restrict__ attn_mask,
    const int* __restrict__ kp_mask, float* __restrict__ probs_out,
    unsigned short* __restrict__ ctxb) {
  int qt = blockIdx.x, h = blockIdx.y, b = blockIdx.z;
  int tid = threadIdx.x;

  __shared__ unsigned short Qs[32 * 72];
  __shared__ unsigned short KV[64 * 72];
  __shared__ unsigned short S[32 * 520];
  __shared__ float invs[32];

  int lane = tid & 63, wave = tid >> 6;
  int l15 = lane & 15, l4 = lane >> 4;

  // Q stage, pre-scaled by 1/8
  {
    int r = tid >> 3, c = (tid & 7) * 8;
    int t = b * Nseq + qt * 32 + r;
    uint4 v = *(const uint4*)(qkvb + (size_t)t * H3 + h * DHd + c);
    unsigned short* u = (unsigned short*)&v;
    unsigned short tmp[8];
#pragma unroll
    for (int j = 0; j < 8; j++) tmp[j] = f2bf(bf2f(u[j]) * 0.125f);
    *(uint4*)&Qs[r * 72 + c] = *(uint4*)tmp;
  }

  // QK^T (raw scores)
  int kr0 = tid >> 3, kc0 = (tid & 7) * 8;
  int kr1 = kr0 + 32;
  for (int kt = 0; kt < 8; kt++) {
    uint4 kv0 = *(const uint4*)(qkvb + (size_t)(b * Nseq + kt * 64 + kr0) * H3 + Hdim + h * DHd + kc0);
    uint4 kv1 = *(const uint4*)(qkvb + (size_t)(b * Nseq + kt * 64 + kr1) * H3 + Hdim + h * DHd + kc0);
    __syncthreads();
    *(uint4*)&KV[kr0 * 72 + kc0] = kv0;
    *(uint4*)&KV[kr1 * 72 + kc0] = kv1;
    __syncthreads();

    f32x4 acc[2] = {};
#pragma unroll
    for (int kk = 0; kk < 2; kk++) {
      short8 bfr = *(const short8*)&KV[(wave * 16 + l15) * 72 + kk * 32 + l4 * 8];
#pragma unroll
      for (int m = 0; m < 2; m++) {
        short8 afr = *(const short8*)&Qs[(m * 16 + l15) * 72 + kk * 32 + l4 * 8];
        acc[m] = __builtin_amdgcn_mfma_f32_16x16x32_bf16(afr, bfr, acc[m], 0, 0, 0);
      }
    }
    int key = kt * 64 + wave * 16 + l15;
#pragma unroll
    for (int m = 0; m < 2; m++) {
#pragma unroll
      for (int r = 0; r < 4; r++) {
        int row = m * 16 + l4 * 4 + r;
        S[row * 520 + key] = f2bf(acc[m][r]);
      }
    }
  }
  __syncthreads();

  // mask + softmax: 8 lanes/row; S <- exp(masked - m) unnormalized
  float inv;
  int sr = tid >> 3, sg = tid & 7;
  {
    unsigned short* Srow = &S[sr * 520];
    const int* amrow = attn_mask + (qt * 32 + sr) * Nseq;
    const int* kprow = kp_mask + b * Nseq;
    float m = -3.0e38f;
#pragma unroll
    for (int i = 0; i < 8; i++) {
      int cb = (sg + 8 * i) * 8;
      uint4 v = *(const uint4*)&Srow[cb];
      unsigned short* u = (unsigned short*)&v;
      int4 a0 = *(const int4*)(amrow + cb);
      int4 a1 = *(const int4*)(amrow + cb + 4);
      int4 k0 = *(const int4*)(kprow + cb);
      int4 k1 = *(const int4*)(kprow + cb + 4);
      float s[8];
      s[0] = bf2f(u[0]) + ((a0.x | k0.x) ? -10000.0f : 0.0f);
      s[1] = bf2f(u[1]) + ((a0.y | k0.y) ? -10000.0f : 0.0f);
      s[2] = bf2f(u[2]) + ((a0.z | k0.z) ? -10000.0f : 0.0f);
      s[3] = bf2f(u[3]) + ((a0.w | k0.w) ? -10000.0f : 0.0f);
      s[4] = bf2f(u[4]) + ((a1.x | k1.x) ? -10000.0f : 0.0f);
      s[5] = bf2f(u[5]) + ((a1.y | k1.y) ? -10000.0f : 0.0f);
      s[6] = bf2f(u[6]) + ((a1.z | k1.z) ? -10000.0f : 0.0f);
      s[7] = bf2f(u[7]) + ((a1.w | k1.w) ? -10000.0f : 0.0f);
      unsigned short t2[8];
#pragma unroll
      for (int j = 0; j < 8; j++) { t2[j] = f2bf(s[j]); m = fmaxf(m, s[j]); }
      *(uint4*)&Srow[cb] = *(uint4*)t2;
    }
#pragma unroll
    for (int off = 1; off < 8; off <<= 1) m = fmaxf(m, __shfl_xor(m, off));
    float sum = 0.f;
#pragma unroll
    for (int i = 0; i < 8; i++) {
      int cb = (sg + 8 * i) * 8;
      uint4 v = *(const uint4*)&Srow[cb];
      unsigned short* u = (unsigned short*)&v;
      unsigned short t2[8];
#pragma unroll
      for (int j = 0; j < 8; j++) {
        float p = expf(bf2f(u[j]) - m);
        t2[j] = f2bf(p);
        sum += p;
      }
      *(uint4*)&Srow[cb] = *(uint4*)t2;
    }
#pragma unroll
    for (int off = 1; off < 8; off <<= 1) sum += __shfl_xor(sum, off);
    inv = 1.0f / sum;
    if (sg == 0) invs[sr] = inv;
  }
  __syncthreads();

  // probs out (fp32, normalized on the fly)
  {
    float* dst = probs_out + (((size_t)(b * NHd + h) * Nseq + qt * 32 + sr) * Nseq);
    const unsigned short* Srow = &S[sr * 520];
#pragma unroll
    for (int i = 0; i < 8; i++) {
      int cb = (sg + 8 * i) * 8;
      uint4 v = *(const uint4*)&Srow[cb];
      unsigned short* u = (unsigned short*)&v;
      float4 o0 = {bf2f(u[0]) * inv, bf2f(u[1]) * inv, bf2f(u[2]) * inv, bf2f(u[3]) * inv};
      float4 o1 = {bf2f(u[4]) * inv, bf2f(u[5]) * inv, bf2f(u[6]) * inv, bf2f(u[7]) * inv};
      *(float4*)(dst + cb)     = o0;
      *(float4*)(dst + cb + 4) = o1;
    }
  }

  // PV: ctx = (S @ V) * inv
  f32x4 acc2[2] = {};
  int kpair = tid & 31, vc = (tid >> 5) * 8;
  for (int kt = 0; kt < 8; kt++) {
    const unsigned short* vsrc =
        qkvb + (size_t)(b * Nseq + kt * 64 + kpair * 2) * H3 + 2 * Hdim + h * DHd + vc;
    uint4 v0 = *(const uint4*)vsrc;
    uint4 v1 = *(const uint4*)(vsrc + H3);
    __syncthreads();
    unsigned* a0 = (unsigned*)&v0;
    unsigned* a1 = (unsigned*)&v1;
#pragma unroll
    for (int i = 0; i < 4; i++) {
      unsigned lo = (a0[i] & 0xffffu) | (a1[i] << 16);
      unsigned hi = (a0[i] >> 16) | (a1[i] & 0xffff0000u);
      *(unsigned*)&KV[(vc + 2 * i    ) * 72 + 2 * kpair] = lo;   // Vt[d][keypair]
      *(unsigned*)&KV[(vc + 2 * i + 1) * 72 + 2 * kpair] = hi;
    }
    __syncthreads();
#pragma unroll
    for (int kk = 0; kk < 2; kk++) {
      short8 bfr = *(const short8*)&KV[(wave * 16 + l15) * 72 + kk * 32 + l4 * 8];
#pragma unroll
      for (int m = 0; m < 2; m++) {
        short8 pfr = *(const short8*)&S[(m * 16 + l15) * 520 + kt * 64 + kk * 32 + l4 * 8];
        acc2[m] = __builtin_amdgcn_mfma_f32_16x16x32_bf16(pfr, bfr, acc2[m], 0, 0, 0);
      }
    }
  }
#pragma unroll
  for (int m = 0; m < 2; m++) {
#pragma unroll
    for (int r = 0; r < 4; r++) {
      int row = m * 16 + l4 * 4 + r;
      int tq = b * Nseq + qt * 32 + row;
      ctxb[(size_t)tq * Hdim + h * DHd + wave * 16 + l15] = f2bf(acc2[m][r] * invs[row]);
    }
  }
}

// ---------------- host ------------------------------------------------------------
extern "C" void kernel_launch(void* const* d_in, const int* in_sizes, int n_in,
                              void* d_out, int out_size, void* d_ws, size_t ws_size,
                              hipStream_t stream) {
  const float* hidden   = (const float*)d_in[0];
  const int*   attn_m   = (const int*)d_in[1];
  const int*   kp_m     = (const int*)d_in[2];
  const float* w_gate   = (const float*)d_in[3];
  const float* w_qkv    = (const float*)d_in[4];
  const float* b_qkv    = (const float*)d_in[5];
  const float* w_dense  = (const float*)d_in[6];
  const float* b_dense  = (const float*)d_in[7];

  float* out       = (float*)d_out;                 // [T,H] fp32
  float* probs_out = out + (size_t)T * Hdim;        // [B,NH,N,N] fp32

  float*          prob = (float*)d_ws;
  unsigned short* Xb   = (unsigned short*)(prob + 2048);
  unsigned short* qkvb = Xb + (size_t)T * Hdim;
  unsigned short* ctxb = qkvb + (size_t)T * H3;
  int*   ip     = (int*)(ctxb + (size_t)T * Hdim);
  int*   expert = ip;
  int*   perm   = ip + T;
  int*   counts = ip + 2 * T;
  int*   offs   = counts + 8;
  int*   cursor = offs + 12;
  int*   meta   = cursor + 8;
  int*   te128  = meta + 4;
  int*   tr128  = te128 + MAXT128;
  int*   te64   = tr128 + MAXT128;
  int*   tr64   = te64 + MAXT64;

  init_kernel<<<1, 64, 0, stream>>>(counts);
  gate_kernel<<<T, 64, 0, stream>>>(hidden, w_gate, prob, expert, counts);
  offsets_kernel<<<1, 1, 0, stream>>>(counts, offs, cursor, meta, te128, tr128, te64, tr64);
  scatter_kernel<<<T / 256, 256, 0, stream>>>(expert, cursor, perm);
  cvt_kernel<<<(T * Hdim / 8) / 256, 256, 0, stream>>>(hidden, Xb, T * Hdim / 8);
  moe_gemm_pipe<128><<<dim3(H3 / 64, MAXT128), 256, 0, stream>>>(
      Xb, w_qkv, b_qkv, prob, perm, offs, meta, te128, tr128, qkvb, nullptr, H3);
  attn_kernel<<<dim3(16, NHd, Bsz), 256, 0, stream>>>(qkvb, attn_m, kp_m, probs_out, ctxb);
  moe_gemm_pipe<64><<<dim3(Hdim / 64, MAXT64), 256, 0, stream>>>(
      ctxb, w_dense, b_dense, prob, perm, offs, meta + 1, te64, tr64, nullptr, out, Hdim);
}